// Round 2
// baseline (231.784 us; speedup 1.0000x reference)
//
#include <hip/hip_runtime.h>
#include <stdint.h>

#define NNODES 200000
#define BNODES 40000
#define DEG    16
#define DFEAT  128
#define DOUT   256
#define NCLS   128
#define TILE   32   // nodes per block

typedef __attribute__((ext_vector_type(8))) __bf16 bf16x8;
typedef __attribute__((ext_vector_type(4))) float  floatx4;

// round-to-nearest-even fp32 -> bf16 bits
__device__ __forceinline__ uint32_t f2bf(float f) {
  uint32_t x = __float_as_uint(f);
  return ((x + 0x7fffu + ((x >> 16) & 1u)) >> 16) & 0xffffu;
}

__device__ __forceinline__ floatx4 b2f4(ushort4 r) {
  floatx4 v;
  v.x = __uint_as_float((uint32_t)r.x << 16);
  v.y = __uint_as_float((uint32_t)r.y << 16);
  v.z = __uint_as_float((uint32_t)r.z << 16);
  v.w = __uint_as_float((uint32_t)r.w << 16);
  return v;
}

__global__ __launch_bounds__(256) void cvt_weights(
    const float* __restrict__ W1, const float* __restrict__ W3,
    uint16_t* __restrict__ w1b, uint16_t* __restrict__ w3b) {
  int i = blockIdx.x * 256 + threadIdx.x;
  if (i < DOUT * 2 * DFEAT) w1b[i] = (uint16_t)f2bf(W1[i]);
  if (i < NCLS * DOUT)      w3b[i] = (uint16_t)f2bf(W3[i]);
}

// fp32 feat -> bf16 table, 8 elems/thread, streaming
__global__ __launch_bounds__(256) void cvt_feat(
    const float* __restrict__ feat, uint16_t* __restrict__ featb) {
  size_t i = ((size_t)blockIdx.x * 256 + threadIdx.x) * 8;
  const float4 a = *(const float4*)(feat + i);
  const float4 b = *(const float4*)(feat + i + 4);
  uint4 p;
  p.x = f2bf(a.x) | (f2bf(a.y) << 16);
  p.y = f2bf(a.z) | (f2bf(a.w) << 16);
  p.z = f2bf(b.x) | (f2bf(b.y) << 16);
  p.w = f2bf(b.z) | (f2bf(b.w) << 16);
  *(uint4*)(featb + i) = p;
}

template <bool BF16T>
__global__ __launch_bounds__(256, 4) void sage_fused(
    const int* __restrict__ inputs, const int* __restrict__ nbr,
    const float* __restrict__ feat, const uint16_t* __restrict__ featb,
    const uint16_t* __restrict__ w1b, const float* __restrict__ b1,
    const uint16_t* __restrict__ w3b, const float* __restrict__ b3,
    float* __restrict__ out) {
  // embL (phases 1-2) and lgL (phases 3-4) alias: 33792 B total => 4 blocks/CU
  __shared__ __align__(16) unsigned char smemA[TILE * 264 * 2];   // 16896 B
  __shared__ __align__(16) uint16_t hL[TILE][264];                // 16896 B
  uint16_t (*embL)[264] = (uint16_t (*)[264])smemA;
  float    (*lgL)[132]  = (float    (*)[132])smemA;

  const int tid  = threadIdx.x;
  const int w    = tid >> 6;       // wave 0..3
  const int lane = tid & 63;
  const int quad = lane >> 4;
  const int l16  = lane & 15;

  // ---------------- Phase 1: gather + segment-mean -> emb (bf16 in LDS) ----
  // Half-wave per node: 32 lanes own 4 dims each. Neighbor rows come from the
  // bf16 table (256 B/row: halves bytes AND cache lines through the random-
  // fetch path); self row stays fp32 for accuracy. Mean accumulates in fp32.
  {
    const int h   = lane >> 5;     // half 0/1
    const int l32 = lane & 31;
    const int col = l32 * 4;       // dims 4l..4l+3
    const int nodeBase = blockIdx.x * TILE + w * 8;
    const float*    fbs = feat + col;
    const uint16_t* fbb = BF16T ? (featb + col) : nullptr;
#pragma unroll
    for (int p = 0; p < 4; ++p) {
      const int node = nodeBase + p * 2 + h;
      const int row  = w * 8 + p * 2 + h;
      const int* nb  = nbr + node * DEG;
      const int4 i0 = *(const int4*)(nb + 0);
      const int4 i1 = *(const int4*)(nb + 4);
      const int4 i2 = *(const int4*)(nb + 8);
      const int4 i3 = *(const int4*)(nb + 12);
      const int self = inputs[node];
      floatx4 s;
      if constexpr (BF16T) {
#define LDB(name, idx) const ushort4 name = *(const ushort4*)(fbb + (size_t)(idx) * DFEAT)
        LDB(r0,  i0.x); LDB(r1,  i0.y); LDB(r2,  i0.z); LDB(r3,  i0.w);
        LDB(r4,  i1.x); LDB(r5,  i1.y); LDB(r6,  i1.z); LDB(r7,  i1.w);
        LDB(r8,  i2.x); LDB(r9,  i2.y); LDB(r10, i2.z); LDB(r11, i2.w);
        LDB(r12, i3.x); LDB(r13, i3.y); LDB(r14, i3.z); LDB(r15, i3.w);
#undef LDB
        s = (((b2f4(r0) + b2f4(r1)) + (b2f4(r2) + b2f4(r3)))
           + ((b2f4(r4) + b2f4(r5)) + (b2f4(r6) + b2f4(r7))))
          + (((b2f4(r8) + b2f4(r9)) + (b2f4(r10) + b2f4(r11)))
           + ((b2f4(r12) + b2f4(r13)) + (b2f4(r14) + b2f4(r15))));
      } else {
#define LDN(name, idx) const floatx4 name = *(const floatx4*)(fbs + (size_t)(idx) * DFEAT)
        LDN(v0,  i0.x); LDN(v1,  i0.y); LDN(v2,  i0.z); LDN(v3,  i0.w);
        LDN(v4,  i1.x); LDN(v5,  i1.y); LDN(v6,  i1.z); LDN(v7,  i1.w);
        LDN(v8,  i2.x); LDN(v9,  i2.y); LDN(v10, i2.z); LDN(v11, i2.w);
        LDN(v12, i3.x); LDN(v13, i3.y); LDN(v14, i3.z); LDN(v15, i3.w);
#undef LDN
        s = (((v0 + v1) + (v2 + v3)) + ((v4 + v5) + (v6 + v7)))
          + (((v8 + v9) + (v10 + v11)) + ((v12 + v13) + (v14 + v15)));
      }
      const floatx4 sv = *(const floatx4*)(fbs + (size_t)self * DFEAT);
      const floatx4 m = s * 0.0625f;
      uint2 selfp, meanp;
      selfp.x = f2bf(sv.x) | (f2bf(sv.y) << 16);
      selfp.y = f2bf(sv.z) | (f2bf(sv.w) << 16);
      meanp.x = f2bf(m.x) | (f2bf(m.y) << 16);
      meanp.y = f2bf(m.z) | (f2bf(m.w) << 16);
      *(uint2*)&embL[row][col]         = selfp;   // self dims 4l..4l+3
      *(uint2*)&embL[row][DFEAT + col] = meanp;   // mean dims 128+4l..
    }
  }
  __syncthreads();

  const int kq = quad * 8;

  // ---------------- Phase 2: h = relu(emb @ W1^T + b1), bf16 -> LDS --------
  {
    floatx4 acc[2][4];
#pragma unroll
    for (int mt = 0; mt < 2; ++mt)
#pragma unroll
      for (int ot = 0; ot < 4; ++ot) {
        floatx4 z = {0.f, 0.f, 0.f, 0.f};
        acc[mt][ot] = z;
      }
#pragma unroll
    for (int kt = 0; kt < 8; ++kt) {
      const int k0 = kt * 32 + kq;
      const bf16x8 a0 = *(const bf16x8*)&embL[l16][k0];
      const bf16x8 a1 = *(const bf16x8*)&embL[16 + l16][k0];
#pragma unroll
      for (int ot = 0; ot < 4; ++ot) {
        const int o = (w * 4 + ot) * 16 + l16;
        const bf16x8 b = *(const bf16x8*)(w1b + o * 256 + k0);
        acc[0][ot] = __builtin_amdgcn_mfma_f32_16x16x32_bf16(a0, b, acc[0][ot], 0, 0, 0);
        acc[1][ot] = __builtin_amdgcn_mfma_f32_16x16x32_bf16(a1, b, acc[1][ot], 0, 0, 0);
      }
    }
#pragma unroll
    for (int ot = 0; ot < 4; ++ot) {
      const int o = (w * 4 + ot) * 16 + l16;
      const float bias = b1[o];
#pragma unroll
      for (int mt = 0; mt < 2; ++mt)
#pragma unroll
        for (int r = 0; r < 4; ++r) {
          float v = acc[mt][ot][r] + bias;
          v = fmaxf(v, 0.f);
          hL[mt * 16 + quad * 4 + r][o] = (uint16_t)f2bf(v);
        }
    }
  }
  __syncthreads();

  // ---------------- Phase 3: logits = h @ W3^T + b3 -> LDS fp32 ------------
  // (writes lgL, which aliases embL -- embL is dead after phase 2's barrier)
  {
    floatx4 acc2[2][2];
#pragma unroll
    for (int mt = 0; mt < 2; ++mt)
#pragma unroll
      for (int ct = 0; ct < 2; ++ct) {
        floatx4 z = {0.f, 0.f, 0.f, 0.f};
        acc2[mt][ct] = z;
      }
#pragma unroll
    for (int kt = 0; kt < 8; ++kt) {
      const int k0 = kt * 32 + kq;
      const bf16x8 a0 = *(const bf16x8*)&hL[l16][k0];
      const bf16x8 a1 = *(const bf16x8*)&hL[16 + l16][k0];
#pragma unroll
      for (int ct = 0; ct < 2; ++ct) {
        const int c = (w * 2 + ct) * 16 + l16;
        const bf16x8 b = *(const bf16x8*)(w3b + c * 256 + k0);
        acc2[0][ct] = __builtin_amdgcn_mfma_f32_16x16x32_bf16(a0, b, acc2[0][ct], 0, 0, 0);
        acc2[1][ct] = __builtin_amdgcn_mfma_f32_16x16x32_bf16(a1, b, acc2[1][ct], 0, 0, 0);
      }
    }
#pragma unroll
    for (int ct = 0; ct < 2; ++ct) {
      const int c = (w * 2 + ct) * 16 + l16;
      const float bias = b3[c];
#pragma unroll
      for (int mt = 0; mt < 2; ++mt)
#pragma unroll
        for (int r = 0; r < 4; ++r)
          lgL[mt * 16 + quad * 4 + r][c] = acc2[mt][ct][r] + bias;
    }
  }
  __syncthreads();

  // ---------------- Phase 4: row L2-normalize + store ----------------------
  {
    const int nr  = tid >> 3;       // node row 0..31
    const int sub = tid & 7;        // 8 threads per row, 16 cols each
    const float* lrow = &lgL[nr][sub * 16];
    float4 v0 = *(const float4*)(lrow + 0);
    float4 v1 = *(const float4*)(lrow + 4);
    float4 v2 = *(const float4*)(lrow + 8);
    float4 v3 = *(const float4*)(lrow + 12);
    float ss = v0.x * v0.x + v0.y * v0.y + v0.z * v0.z + v0.w * v0.w
             + v1.x * v1.x + v1.y * v1.y + v1.z * v1.z + v1.w * v1.w
             + v2.x * v2.x + v2.y * v2.y + v2.z * v2.z + v2.w * v2.w
             + v3.x * v3.x + v3.y * v3.y + v3.z * v3.z + v3.w * v3.w;
    ss += __shfl_xor(ss, 1);
    ss += __shfl_xor(ss, 2);
    ss += __shfl_xor(ss, 4);
    const float scale = 1.f / fmaxf(sqrtf(ss), 1e-12f);
    v0.x *= scale; v0.y *= scale; v0.z *= scale; v0.w *= scale;
    v1.x *= scale; v1.y *= scale; v1.z *= scale; v1.w *= scale;
    v2.x *= scale; v2.y *= scale; v2.z *= scale; v2.w *= scale;
    v3.x *= scale; v3.y *= scale; v3.z *= scale; v3.w *= scale;
    float* op = out + ((size_t)(blockIdx.x * TILE + nr)) * NCLS + sub * 16;
    *(float4*)(op + 0)  = v0;
    *(float4*)(op + 4)  = v1;
    *(float4*)(op + 8)  = v2;
    *(float4*)(op + 12) = v3;
  }
}

extern "C" void kernel_launch(void* const* d_in, const int* in_sizes, int n_in,
                              void* d_out, int out_size, void* d_ws, size_t ws_size,
                              hipStream_t stream) {
  const int*   inputs = (const int*)d_in[0];
  const int*   nbr    = (const int*)d_in[1];
  // d_in[2] segment_ids: regular repeat(arange(B), 16) -> implicit, unused
  const float* feat   = (const float*)d_in[3];
  const float* W1     = (const float*)d_in[4];
  const float* b1     = (const float*)d_in[5];
  const float* W3     = (const float*)d_in[6];
  const float* b3     = (const float*)d_in[7];

  uint16_t* w1b   = (uint16_t*)d_ws;               // 256*256 bf16 = 128 KiB
  uint16_t* w3b   = w1b + DOUT * 2 * DFEAT;        // 128*256 bf16 =  64 KiB
  uint16_t* featb = w3b + NCLS * DOUT;             // 200000*128 bf16 = 51.2 MB

  const size_t need = ((size_t)(DOUT * 2 * DFEAT + NCLS * DOUT)
                     + (size_t)NNODES * DFEAT) * sizeof(uint16_t);

  cvt_weights<<<(DOUT * 2 * DFEAT) / 256, 256, 0, stream>>>(W1, W3, w1b, w3b);
  if (ws_size >= need) {
    cvt_feat<<<(NNODES * DFEAT) / (256 * 8), 256, 0, stream>>>(feat, featb);
    sage_fused<true><<<BNODES / TILE, 256, 0, stream>>>(
        inputs, nbr, feat, featb, w1b, b1, w3b, b3, (float*)d_out);
  } else {
    sage_fused<false><<<BNODES / TILE, 256, 0, stream>>>(
        inputs, nbr, feat, nullptr, w1b, b1, w3b, b3, (float*)d_out);
  }
}

// Round 3
// 218.913 us; speedup vs baseline: 1.0588x; 1.0588x over previous
//
#include <hip/hip_runtime.h>
#include <stdint.h>

#define NNODES 200000
#define BNODES 40000
#define DEG    16
#define DFEAT  128
#define DOUT   256
#define NCLS   128
#define TILE   32   // nodes per block

typedef __attribute__((ext_vector_type(8))) __bf16 bf16x8;
typedef __attribute__((ext_vector_type(4))) float  floatx4;

// round-to-nearest-even fp32 -> bf16 bits
__device__ __forceinline__ uint32_t f2bf(float f) {
  uint32_t x = __float_as_uint(f);
  return ((x + 0x7fffu + ((x >> 16) & 1u)) >> 16) & 0xffffu;
}

__global__ __launch_bounds__(256) void cvt_weights(
    const float* __restrict__ W1, const float* __restrict__ W3,
    uint16_t* __restrict__ w1b, uint16_t* __restrict__ w3b) {
  int i = blockIdx.x * 256 + threadIdx.x;
  if (i < DOUT * 2 * DFEAT) w1b[i] = (uint16_t)f2bf(W1[i]);
  if (i < NCLS * DOUT)      w3b[i] = (uint16_t)f2bf(W3[i]);
}

__global__ __launch_bounds__(256, 4) void sage_fused(
    const int* __restrict__ inputs, const int* __restrict__ nbr,
    const float* __restrict__ feat,
    const uint16_t* __restrict__ w1b, const float* __restrict__ b1,
    const uint16_t* __restrict__ w3b, const float* __restrict__ b3,
    float* __restrict__ out) {
  // embL (phases 1-2) and lgL (phases 3-4) alias: 33792 B total => 4 blocks/CU
  __shared__ __align__(16) unsigned char smemA[TILE * 264 * 2];   // 16896 B
  __shared__ __align__(16) uint16_t hL[TILE][264];                // 16896 B
  uint16_t (*embL)[264] = (uint16_t (*)[264])smemA;
  float    (*lgL)[132]  = (float    (*)[132])smemA;

  const int tid  = threadIdx.x;
  // readfirstlane: make the wave index provably uniform so neighbor-id and
  // self-id reads become SGPR s_loads (frees VGPRs for the load batch).
  const int w    = __builtin_amdgcn_readfirstlane(tid >> 6);   // wave 0..3
  const int lane = tid & 63;
  const int quad = lane >> 4;
  const int l16  = lane & 15;

  // ---------------- Phase 1: gather + segment-mean -> emb (bf16 in LDS) ----
  // One full 512B fp32 row per 32-lane half (float4/lane); one wave VMEM
  // instruction = 2 neighbor rows. 8 VMEM instrs cover all 16 neighbors.
  // Two nodes' loads (18 VMEM, ~17KB) are issued before either reduction:
  // deep MLP so the random-gather latency is covered by bytes in flight.
  {
    const int h   = lane >> 5;     // half 0/1
    const int l32 = lane & 31;
    const int nodeBase = blockIdx.x * TILE + w * 8;
    const float* fcol = feat + l32 * 4;     // dims 4*l32 .. 4*l32+3
#pragma unroll
    for (int pp = 0; pp < 8; pp += 2) {
      const int nodeA = nodeBase + pp;
      const int nodeB = nodeBase + pp + 1;
      const int* nbA = nbr + nodeA * DEG;   // wave-uniform -> s_load
      const int* nbB = nbr + nodeB * DEG;
      const int selfA = inputs[nodeA];
      const int selfB = inputs[nodeB];
      // ---- issue all loads for A then B (36 VGPRs of results in flight) --
      floatx4 a0, a1, a2, a3, a4, a5, a6, a7;
      floatx4 c0, c1, c2, c3, c4, c5, c6, c7;
#define LDP(dst, nb, g)                                                      \
  {                                                                          \
    const int id_ = h ? (nb)[2 * (g) + 1] : (nb)[2 * (g)];                   \
    dst = *(const floatx4*)(fcol + (size_t)id_ * DFEAT);                     \
  }
      LDP(a0, nbA, 0) LDP(a1, nbA, 1) LDP(a2, nbA, 2) LDP(a3, nbA, 3)
      LDP(a4, nbA, 4) LDP(a5, nbA, 5) LDP(a6, nbA, 6) LDP(a7, nbA, 7)
      const float2 svA = *(const float2*)(feat + (size_t)selfA * DFEAT + lane * 2);
      LDP(c0, nbB, 0) LDP(c1, nbB, 1) LDP(c2, nbB, 2) LDP(c3, nbB, 3)
      LDP(c4, nbB, 4) LDP(c5, nbB, 5) LDP(c6, nbB, 6) LDP(c7, nbB, 7)
      const float2 svB = *(const float2*)(feat + (size_t)selfB * DFEAT + lane * 2);
#undef LDP
      // ---- reduce + write A ---------------------------------------------
      {
        floatx4 s = ((a0 + a1) + (a2 + a3)) + ((a4 + a5) + (a6 + a7));
        s.x += __shfl_xor(s.x, 32);   // combine the two halves' 8-row sums
        s.y += __shfl_xor(s.y, 32);
        s.z += __shfl_xor(s.z, 32);
        s.w += __shfl_xor(s.w, 32);
        const floatx4 m = s * 0.0625f;
        const int row = w * 8 + pp;
        *(uint32_t*)&embL[row][lane * 2] = f2bf(svA.x) | (f2bf(svA.y) << 16);
        if (h == 0) {
          uint2 mp;
          mp.x = f2bf(m.x) | (f2bf(m.y) << 16);
          mp.y = f2bf(m.z) | (f2bf(m.w) << 16);
          *(uint2*)&embL[row][DFEAT + l32 * 4] = mp;
        }
      }
      // ---- reduce + write B ---------------------------------------------
      {
        floatx4 s = ((c0 + c1) + (c2 + c3)) + ((c4 + c5) + (c6 + c7));
        s.x += __shfl_xor(s.x, 32);
        s.y += __shfl_xor(s.y, 32);
        s.z += __shfl_xor(s.z, 32);
        s.w += __shfl_xor(s.w, 32);
        const floatx4 m = s * 0.0625f;
        const int row = w * 8 + pp + 1;
        *(uint32_t*)&embL[row][lane * 2] = f2bf(svB.x) | (f2bf(svB.y) << 16);
        if (h == 0) {
          uint2 mp;
          mp.x = f2bf(m.x) | (f2bf(m.y) << 16);
          mp.y = f2bf(m.z) | (f2bf(m.w) << 16);
          *(uint2*)&embL[row][DFEAT + l32 * 4] = mp;
        }
      }
    }
  }
  __syncthreads();

  const int kq = quad * 8;

  // ---------------- Phase 2: h = relu(emb @ W1^T + b1), bf16 -> LDS --------
  {
    floatx4 acc[2][4];
#pragma unroll
    for (int mt = 0; mt < 2; ++mt)
#pragma unroll
      for (int ot = 0; ot < 4; ++ot) {
        floatx4 z = {0.f, 0.f, 0.f, 0.f};
        acc[mt][ot] = z;
      }
#pragma unroll
    for (int kt = 0; kt < 8; ++kt) {
      const int k0 = kt * 32 + kq;
      const bf16x8 a0 = *(const bf16x8*)&embL[l16][k0];
      const bf16x8 a1 = *(const bf16x8*)&embL[16 + l16][k0];
#pragma unroll
      for (int ot = 0; ot < 4; ++ot) {
        const int o = (w * 4 + ot) * 16 + l16;
        const bf16x8 b = *(const bf16x8*)(w1b + o * 256 + k0);
        acc[0][ot] = __builtin_amdgcn_mfma_f32_16x16x32_bf16(a0, b, acc[0][ot], 0, 0, 0);
        acc[1][ot] = __builtin_amdgcn_mfma_f32_16x16x32_bf16(a1, b, acc[1][ot], 0, 0, 0);
      }
    }
#pragma unroll
    for (int ot = 0; ot < 4; ++ot) {
      const int o = (w * 4 + ot) * 16 + l16;
      const float bias = b1[o];
#pragma unroll
      for (int mt = 0; mt < 2; ++mt)
#pragma unroll
        for (int r = 0; r < 4; ++r) {
          float v = acc[mt][ot][r] + bias;
          v = fmaxf(v, 0.f);
          hL[mt * 16 + quad * 4 + r][o] = (uint16_t)f2bf(v);
        }
    }
  }
  __syncthreads();

  // ---------------- Phase 3: logits = h @ W3^T + b3 -> LDS fp32 ------------
  // (writes lgL, which aliases embL -- embL is dead after phase 2's barrier)
  {
    floatx4 acc2[2][2];
#pragma unroll
    for (int mt = 0; mt < 2; ++mt)
#pragma unroll
      for (int ct = 0; ct < 2; ++ct) {
        floatx4 z = {0.f, 0.f, 0.f, 0.f};
        acc2[mt][ct] = z;
      }
#pragma unroll
    for (int kt = 0; kt < 8; ++kt) {
      const int k0 = kt * 32 + kq;
      const bf16x8 a0 = *(const bf16x8*)&hL[l16][k0];
      const bf16x8 a1 = *(const bf16x8*)&hL[16 + l16][k0];
#pragma unroll
      for (int ct = 0; ct < 2; ++ct) {
        const int c = (w * 2 + ct) * 16 + l16;
        const bf16x8 b = *(const bf16x8*)(w3b + c * 256 + k0);
        acc2[0][ct] = __builtin_amdgcn_mfma_f32_16x16x32_bf16(a0, b, acc2[0][ct], 0, 0, 0);
        acc2[1][ct] = __builtin_amdgcn_mfma_f32_16x16x32_bf16(a1, b, acc2[1][ct], 0, 0, 0);
      }
    }
#pragma unroll
    for (int ct = 0; ct < 2; ++ct) {
      const int c = (w * 2 + ct) * 16 + l16;
      const float bias = b3[c];
#pragma unroll
      for (int mt = 0; mt < 2; ++mt)
#pragma unroll
        for (int r = 0; r < 4; ++r)
          lgL[mt * 16 + quad * 4 + r][c] = acc2[mt][ct][r] + bias;
    }
  }
  __syncthreads();

  // ---------------- Phase 4: row L2-normalize + store ----------------------
  {
    const int nr  = tid >> 3;       // node row 0..31
    const int sub = tid & 7;        // 8 threads per row, 16 cols each
    const float* lrow = &lgL[nr][sub * 16];
    float4 v0 = *(const float4*)(lrow + 0);
    float4 v1 = *(const float4*)(lrow + 4);
    float4 v2 = *(const float4*)(lrow + 8);
    float4 v3 = *(const float4*)(lrow + 12);
    float ss = v0.x * v0.x + v0.y * v0.y + v0.z * v0.z + v0.w * v0.w
             + v1.x * v1.x + v1.y * v1.y + v1.z * v1.z + v1.w * v1.w
             + v2.x * v2.x + v2.y * v2.y + v2.z * v2.z + v2.w * v2.w
             + v3.x * v3.x + v3.y * v3.y + v3.z * v3.z + v3.w * v3.w;
    ss += __shfl_xor(ss, 1);
    ss += __shfl_xor(ss, 2);
    ss += __shfl_xor(ss, 4);
    const float scale = 1.f / fmaxf(sqrtf(ss), 1e-12f);
    v0.x *= scale; v0.y *= scale; v0.z *= scale; v0.w *= scale;
    v1.x *= scale; v1.y *= scale; v1.z *= scale; v1.w *= scale;
    v2.x *= scale; v2.y *= scale; v2.z *= scale; v2.w *= scale;
    v3.x *= scale; v3.y *= scale; v3.z *= scale; v3.w *= scale;
    float* op = out + ((size_t)(blockIdx.x * TILE + nr)) * NCLS + sub * 16;
    *(float4*)(op + 0)  = v0;
    *(float4*)(op + 4)  = v1;
    *(float4*)(op + 8)  = v2;
    *(float4*)(op + 12) = v3;
  }
}

extern "C" void kernel_launch(void* const* d_in, const int* in_sizes, int n_in,
                              void* d_out, int out_size, void* d_ws, size_t ws_size,
                              hipStream_t stream) {
  const int*   inputs = (const int*)d_in[0];
  const int*   nbr    = (const int*)d_in[1];
  // d_in[2] segment_ids: regular repeat(arange(B), 16) -> implicit, unused
  const float* feat   = (const float*)d_in[3];
  const float* W1     = (const float*)d_in[4];
  const float* b1     = (const float*)d_in[5];
  const float* W3     = (const float*)d_in[6];
  const float* b3     = (const float*)d_in[7];

  uint16_t* w1b = (uint16_t*)d_ws;                 // 256*256 bf16
  uint16_t* w3b = w1b + DOUT * 2 * DFEAT;          // 128*256 bf16 (total 192 KiB ws)

  cvt_weights<<<(DOUT * 2 * DFEAT) / 256, 256, 0, stream>>>(W1, W3, w1b, w3b);
  sage_fused<<<BNODES / TILE, 256, 0, stream>>>(inputs, nbr, feat, w1b, b1, w3b, b3,
                                                (float*)d_out);
}